// Round 2
// baseline (904.118 us; speedup 1.0000x reference)
//
#include <hip/hip_runtime.h>
#include <math.h>

#define B 32
#define NBOX 24564
#define NCLS 81
#define ROWLEN 93
#define CONF_T 0.5f
#define IOU_T 0.35f
#define NUM_PRED 10
#define IMG_W 512.0f
#define IMG_H 512.0f

#define BPB 64                                   // boxes per block in decode
#define K1_THREADS 256
#define NBLK ((NBOX + BPB - 1) / BPB)            // 384 blocks per image

#define K2T 1024
#define NPER ((NBOX + K2T - 1) / K2T)            // 24 register slots per thread

// ---------------- Kernel 1: decode + argmax + candidate compaction ----------
// 256 threads / 64 boxes. Stage the block's 64*93 floats via float4 (chunk is
// 16B-aligned: 64*93*4 = 23808 B per block, image stride also 16B-aligned).
// 4 lanes per box reduce the 81-class argmax; q==0 lane decodes the box and,
// if (cls!=0 && score>=0.5), appends {box,score,cls} to the per-image
// candidate list via wave-aggregated atomicAdd.
__global__ __launch_bounds__(K1_THREADS) void decode_kernel(
    const float* __restrict__ y, float4* __restrict__ candBox,
    float2* __restrict__ candSc, int* __restrict__ cnt)
{
    __shared__ float4 lds4[(BPB * ROWLEN) / 4];  // 1488 float4 = 23808 B
    float* lds = (float*)lds4;
    int bid  = blockIdx.x;
    int b    = bid / NBLK;
    int blk  = bid % NBLK;
    int box0 = blk * BPB;
    int nb   = NBOX - box0; if (nb > BPB) nb = BPB;   // 64 or 52 (both %4==0)
    int n4   = (nb * ROWLEN) / 4;
    const float4* src = (const float4*)(y + ((size_t)b * NBOX + box0) * ROWLEN);
    for (int k = threadIdx.x; k < n4; k += K1_THREADS)
        lds4[k] = src[k];
    __syncthreads();

    int q  = threadIdx.x & 3;                    // lane quad within a box
    int bl = threadIdx.x >> 2;                   // local box index
    int lane = threadIdx.x & 63;
    bool have = (bl < nb);
    const float* row = &lds[bl * ROWLEN];

    // strided partial argmax; strict '>' keeps first occurrence per lane
    float best = -INFINITY; int bci = 0x7fffffff;
    if (have) {
        for (int c = q; c < NCLS; c += 4) {
            float v = row[c];
            if (v > best) { best = v; bci = c; }
        }
    }
    // combine 4 lanes; tie-break smallest class index (jnp.argmax = first)
    #pragma unroll
    for (int m = 1; m <= 2; m <<= 1) {
        float ov = __shfl_xor(best, m, 64);
        int   oi = __shfl_xor(bci,  m, 64);
        if (ov > best || (ov == best && oi < bci)) { best = ov; bci = oi; }
    }

    float4 bx; bool valid = false;
    if (have && q == 0) {
        const float* t = row + NCLS;             // [off0..3, acx, acy, aw, ah, v0..3]
        float cx = t[0] * t[8]  * t[6] + t[4];
        float cy = t[1] * t[9]  * t[7] + t[5];
        float w  = expf(t[2] * t[10]) * t[6];
        float h  = expf(t[3] * t[11]) * t[7];
        bx.x = (cx - 0.5f * w) * IMG_W;
        bx.y = (cy - 0.5f * h) * IMG_H;
        bx.z = (cx + 0.5f * w) * IMG_W;
        bx.w = (cy + 0.5f * h) * IMG_H;
        valid = (bci != 0) && (best >= CONF_T);
    }

    // wave-aggregated append (all 64 lanes participate in the ballot)
    unsigned long long mask = __ballot(valid);
    int n = __popcll(mask);
    int base = 0;
    if (lane == 0 && n) base = atomicAdd(&cnt[b], n);
    base = __shfl(base, 0, 64);
    if (valid) {
        int slot = base + __popcll(mask & ((1ull << lane) - 1ull));
        size_t g = (size_t)b * NBOX + slot;
        candBox[g] = bx;
        candSc[g]  = make_float2(best, (float)bci);
    }
}

// ---------------- Kernel 2: greedy NMS over compacted candidates ------------
// One block per image. Greedy picks are emitted in non-increasing score order,
// so top_k(kept,10) == first 10 picks; 10 rounds of (argmax -> suppress).
__global__ __launch_bounds__(K2T) void nms_kernel(
    const float4* __restrict__ candBox, const float2* __restrict__ candSc,
    const int* __restrict__ cnt, float* __restrict__ out)
{
    __shared__ float pv[16];
    __shared__ int   pi[16];
    __shared__ float bvS;
    __shared__ int   biS;
    int b = blockIdx.x, tid = threadIdx.x;
    int lane = tid & 63, wid = tid >> 6;
    int M = cnt[b]; if (M > NBOX) M = NBOX;
    const float4* bxp = candBox + (size_t)b * NBOX;
    const float2* sgp = candSc  + (size_t)b * NBOX;

    float sc[NPER];
    #pragma unroll
    for (int j = 0; j < NPER; j++) {
        int g = j * K2T + tid;
        sc[j] = (g < M) ? sgp[g].x : -INFINITY;
    }

    for (int r = 0; r < NUM_PRED; r++) {
        // local scan (ties between distinct candidates are measure-zero)
        float v = -INFINITY; int idx = -1;
        #pragma unroll
        for (int j = 0; j < NPER; j++) {
            int g = j * K2T + tid;
            if (sc[j] > v) { v = sc[j]; idx = g; }
        }
        // wave reduce (no barriers)
        #pragma unroll
        for (int m = 1; m < 64; m <<= 1) {
            float ov = __shfl_xor(v, m, 64);
            int   oi = __shfl_xor(idx, m, 64);
            if (ov > v) { v = ov; idx = oi; }
        }
        if (lane == 0) { pv[wid] = v; pi[wid] = idx; }
        __syncthreads();
        if (wid == 0) {
            float v2 = (lane < 16) ? pv[lane] : -INFINITY;
            int   i2 = (lane < 16) ? pi[lane] : -1;
            #pragma unroll
            for (int m = 1; m < 16; m <<= 1) {
                float ov = __shfl_xor(v2, m, 64);
                int   oi = __shfl_xor(i2, m, 64);
                if (ov > v2) { v2 = ov; i2 = oi; }
            }
            if (lane == 0) { bvS = v2; biS = i2; }
        }
        __syncthreads();
        float bv = bvS; int bi = biS;

        if (!(bv > -INFINITY)) {                 // uniform: exhausted
            if (tid == 0) {
                for (int rr = r; rr < NUM_PRED; rr++) {
                    float* o = out + ((size_t)b * NUM_PRED + rr) * 6;
                    for (int k = 0; k < 6; k++) o[k] = 0.0f;
                }
            }
            break;
        }

        float4 qb = bxp[bi];                     // broadcast (same addr all lanes)
        if (tid == 0) {
            float* o = out + ((size_t)b * NUM_PRED + r) * 6;
            o[0] = sgp[bi].y; o[1] = bv;
            o[2] = qb.x; o[3] = qb.y; o[4] = qb.z; o[5] = qb.w;
        }
        float aq = (qb.z - qb.x) * (qb.w - qb.y);
        #pragma unroll
        for (int j = 0; j < NPER; j++) {
            int g = j * K2T + tid;
            if (g < M && sc[j] > -INFINITY) {
                float4 p = bxp[g];
                float iw = fmaxf(fminf(p.z, qb.z) - fmaxf(p.x, qb.x), 0.0f);
                float ih = fmaxf(fminf(p.w, qb.w) - fmaxf(p.y, qb.y), 0.0f);
                float inter = iw * ih;
                float ab = (p.z - p.x) * (p.w - p.y);
                float iou = inter / (ab + aq - inter + 1e-12f);
                if (iou > IOU_T) sc[j] = -INFINITY;  // also kills the pick itself
            }
        }
        __syncthreads();
    }
}

extern "C" void kernel_launch(void* const* d_in, const int* in_sizes, int n_in,
                              void* d_out, int out_size, void* d_ws, size_t ws_size,
                              hipStream_t stream) {
    const float* y = (const float*)d_in[0];
    float* out = (float*)d_out;
    char* ws = (char*)d_ws;
    // ws layout: candBox (B*NBOX float4) | candSc (B*NBOX float2) | cnt (B int)
    float4* candBox = (float4*)ws;
    float2* candSc  = (float2*)(ws + (size_t)B * NBOX * sizeof(float4));
    int*    cnt     = (int*)(ws + (size_t)B * NBOX * (sizeof(float4) + sizeof(float2)));

    hipMemsetAsync(cnt, 0, B * sizeof(int), stream);
    decode_kernel<<<B * NBLK, K1_THREADS, 0, stream>>>(y, candBox, candSc, cnt);
    nms_kernel<<<B, K2T, 0, stream>>>(candBox, candSc, cnt, out);
}

// Round 3
// 454.741 us; speedup vs baseline: 1.9882x; 1.9882x over previous
//
#include <hip/hip_runtime.h>
#include <math.h>

#define B 32
#define NBOX 24564
#define NCLS 81
#define ROWLEN 93
#define CONF_T 0.5f
#define IOU_T 0.35f
#define NUM_PRED 10
#define IMG_W 512.0f
#define IMG_H 512.0f

#define BPB 64                                   // boxes per block in decode
#define K1_THREADS 256
#define NBLK ((NBOX + BPB - 1) / BPB)            // 384 blocks per image

#define K2T 1024
#define NPER ((NBOX + K2T - 1) / K2T)            // 24 register slots per thread

// ---------------- Kernel 1: decode + class argmax (pure streaming) ----------
// 256 threads / 64 boxes. Stage the block's 64*93 floats via float4 loads
// (chunk is 16B-aligned: 23808 B/block), 4 lanes per box reduce the 81-class
// argmax, lane q==0 decodes the box. NO atomics: dense output arrays,
// score = -inf for invalid boxes.
__global__ __launch_bounds__(K1_THREADS) void decode_kernel(
    const float* __restrict__ y, float4* __restrict__ boxes,
    float* __restrict__ scores, float* __restrict__ clsid)
{
    __shared__ float4 lds4[(BPB * ROWLEN) / 4];  // 1488 float4 = 23808 B
    float* lds = (float*)lds4;
    int bid  = blockIdx.x;
    int b    = bid / NBLK;
    int blk  = bid % NBLK;
    int box0 = blk * BPB;
    int nb   = NBOX - box0; if (nb > BPB) nb = BPB;   // 64 or 52 (both %4==0)
    int n4   = (nb * ROWLEN) / 4;
    const float4* src = (const float4*)(y + ((size_t)b * NBOX + box0) * ROWLEN);
    for (int k = threadIdx.x; k < n4; k += K1_THREADS)
        lds4[k] = src[k];
    __syncthreads();

    int q  = threadIdx.x & 3;                    // lane quad within a box
    int bl = threadIdx.x >> 2;                   // local box index
    if (bl >= nb) return;
    const float* row = &lds[bl * ROWLEN];

    // strided partial argmax; strict '>' keeps first occurrence per lane
    float best = -INFINITY; int bci = 0x7fffffff;
    for (int c = q; c < NCLS; c += 4) {
        float v = row[c];
        if (v > best) { best = v; bci = c; }
    }
    // combine 4 lanes; tie-break smallest class index (jnp.argmax = first)
    #pragma unroll
    for (int m = 1; m <= 2; m <<= 1) {
        float ov = __shfl_xor(best, m, 64);
        int   oi = __shfl_xor(bci,  m, 64);
        if (ov > best || (ov == best && oi < bci)) { best = ov; bci = oi; }
    }

    if (q == 0) {
        const float* t = row + NCLS;             // [off0..3, acx, acy, aw, ah, v0..3]
        float cx = t[0] * t[8]  * t[6] + t[4];
        float cy = t[1] * t[9]  * t[7] + t[5];
        float w  = expf(t[2] * t[10]) * t[6];
        float h  = expf(t[3] * t[11]) * t[7];
        float4 bx;
        bx.x = (cx - 0.5f * w) * IMG_W;
        bx.y = (cy - 0.5f * h) * IMG_H;
        bx.z = (cx + 0.5f * w) * IMG_W;
        bx.w = (cy + 0.5f * h) * IMG_H;
        size_t g = (size_t)b * NBOX + box0 + bl;
        boxes[g] = bx;
        clsid[g] = (float)bci;
        bool valid = (bci != 0) && (best >= CONF_T);
        scores[g] = valid ? best : -INFINITY;
    }
}

// ---------------- Kernel 2: greedy NMS, fused suppress+argmax ---------------
// One block per image; scores live in registers (24/thread). Greedy picks are
// emitted in non-increasing score order, so top_k(kept,10) == first 10 picks.
// Round r: suppress with pick r-1 while scanning for the new max (one pass).
__global__ __launch_bounds__(K2T) void nms_kernel(
    const float4* __restrict__ boxes, const float* __restrict__ scores,
    const float* __restrict__ clsid, float* __restrict__ out)
{
    __shared__ float pv[16];
    __shared__ int   pi[16];
    __shared__ float bvS;
    __shared__ int   biS;
    int b = blockIdx.x, tid = threadIdx.x;
    int lane = tid & 63, wid = tid >> 6;
    const float4* bxp = boxes  + (size_t)b * NBOX;
    const float*  scp = scores + (size_t)b * NBOX;

    float sc[NPER];
    #pragma unroll
    for (int j = 0; j < NPER; j++) {
        int g = j * K2T + tid;
        sc[j] = (g < NBOX) ? scp[g] : -INFINITY;
    }

    float4 qb = make_float4(0.f, 0.f, 0.f, 0.f);
    float  aq = 0.f;
    bool   have_pick = false;

    for (int r = 0; r < NUM_PRED; r++) {
        // fused: suppress vs previous pick + local argmax, single pass
        float v = -INFINITY; int idx = -1;
        #pragma unroll
        for (int j = 0; j < NPER; j++) {
            float s = sc[j];
            if (s > -INFINITY) {
                if (have_pick) {
                    int g = j * K2T + tid;
                    float4 p = bxp[g];
                    float iw = fmaxf(fminf(p.z, qb.z) - fmaxf(p.x, qb.x), 0.0f);
                    float ih = fmaxf(fminf(p.w, qb.w) - fmaxf(p.y, qb.y), 0.0f);
                    float inter = iw * ih;
                    float ab = (p.z - p.x) * (p.w - p.y);
                    float iou = inter / (ab + aq - inter + 1e-12f);
                    if (iou > IOU_T) { s = -INFINITY; sc[j] = s; }
                }
                if (s > v) { v = s; idx = j * K2T + tid; }
            }
        }
        // wave argmax (ties measure-zero; scores are distinct reals)
        #pragma unroll
        for (int m = 1; m < 64; m <<= 1) {
            float ov = __shfl_xor(v, m, 64);
            int   oi = __shfl_xor(idx, m, 64);
            if (ov > v) { v = ov; idx = oi; }
        }
        if (lane == 0) { pv[wid] = v; pi[wid] = idx; }
        __syncthreads();
        if (wid == 0) {
            float v2 = (lane < 16) ? pv[lane] : -INFINITY;
            int   i2 = (lane < 16) ? pi[lane] : -1;
            #pragma unroll
            for (int m = 1; m < 16; m <<= 1) {
                float ov = __shfl_xor(v2, m, 64);
                int   oi = __shfl_xor(i2, m, 64);
                if (ov > v2) { v2 = ov; i2 = oi; }
            }
            if (lane == 0) { bvS = v2; biS = i2; }
        }
        __syncthreads();
        float bv = bvS; int bi = biS;

        if (!(bv > -INFINITY)) {                 // uniform: exhausted
            if (tid == 0) {
                for (int rr = r; rr < NUM_PRED; rr++) {
                    float* o = out + ((size_t)b * NUM_PRED + rr) * 6;
                    for (int k = 0; k < 6; k++) o[k] = 0.0f;
                }
            }
            return;
        }

        qb = bxp[bi];                            // same addr all lanes: broadcast
        aq = (qb.z - qb.x) * (qb.w - qb.y);
        have_pick = true;
        if (tid == 0) {
            float* o = out + ((size_t)b * NUM_PRED + r) * 6;
            o[0] = clsid[(size_t)b * NBOX + bi];
            o[1] = bv;
            o[2] = qb.x; o[3] = qb.y; o[4] = qb.z; o[5] = qb.w;
        }
        // no extra barrier needed: next round's pv/pi writes happen after the
        // next scan; this round's pv/pi reads completed before barrier 2.
    }
}

extern "C" void kernel_launch(void* const* d_in, const int* in_sizes, int n_in,
                              void* d_out, int out_size, void* d_ws, size_t ws_size,
                              hipStream_t stream) {
    const float* y = (const float*)d_in[0];
    float* out = (float*)d_out;
    char* ws = (char*)d_ws;
    // ws layout: boxes (B*NBOX float4) | scores (B*NBOX f32) | clsid (B*NBOX f32)
    float4* boxes  = (float4*)ws;
    float*  scores = (float*)(ws + (size_t)B * NBOX * sizeof(float4));
    float*  clsidp = scores + (size_t)B * NBOX;

    decode_kernel<<<B * NBLK, K1_THREADS, 0, stream>>>(y, boxes, scores, clsidp);
    nms_kernel<<<B, K2T, 0, stream>>>(boxes, scores, clsidp, out);
}